// Round 6
// baseline (139.325 us; speedup 1.0000x reference)
//
#include <hip/hip_runtime.h>
#include <hip/hip_bf16.h>
#include <stdint.h>

// Problem constants (fixed shapes from reference: B=4096, D=256, N=2B)
#define NROWS 8192
#define DDIM  256
#define BM    128
#define BN    128
#define BK    64
#define NTILE (NROWS / BM)              // 64 tile-rows
#define NTRI  (NTILE * (NTILE + 1) / 2) // 2080 upper-tri tiles
#define L2E   1.44269504088896340736f

// LDS: staging A (16 KB) + B (16 KB) = 32 KB. Epilogue scratch aliases it:
//   colAP: float2 [128 cols][5 slots]  @0     = 5120 B (stride 10 dw: conflict-free)
//   rowAP: float2 [128 rows][18 slots] @5120  = 18432 B (stride 36 dw = 16-bank
//          offset -> uniform 2-way = free; rows 16B-aligned)
//   flag/red for the fused finalize @24064.
#define COL_STRIDE2 5
#define ROW_STRIDE2 18
#define ROWAP_OFF   5120
#define SMEM_BYTES  32768

// Workspace layout (unchanged footprint vs r5; lab array dropped):
#define WS_INVW (4u * 1024 * 1024)
#define WS_SALL (WS_INVW + 32 * 1024)
#define WS_SPOS (WS_SALL + 32 * 1024)
#define WS_DONE (WS_SPOS + 32 * 1024)

typedef __attribute__((ext_vector_type(8))) short short8;
typedef __attribute__((ext_vector_type(4))) float f32x4;

typedef const __attribute__((address_space(1))) uint32_t glb_u32;
typedef __attribute__((address_space(3))) uint32_t lds_u32;

__device__ __forceinline__ void load_lds16(const unsigned short* g, unsigned short* l) {
  // 16B per lane, LDS dest = wave-uniform base + lane*16 (HW scatter)
  __builtin_amdgcn_global_load_lds((glb_u32*)g, (lds_u32*)l, 16, 0, 0);
}

__device__ __forceinline__ unsigned short f2bf(float x) {
  __hip_bfloat16 h = __float2bfloat16(x);
  return *reinterpret_cast<unsigned short*>(&h);
}

// Kernel 1: build bf16 concat(f), inv norms (fp32), zero S arrays + done flag.
__global__ void __launch_bounds__(256)
milnce_prep(const float* __restrict__ feat, const float* __restrict__ pos,
            unsigned short* __restrict__ fb, float* __restrict__ inv_w,
            float* __restrict__ S_all, float* __restrict__ S_pos,
            unsigned int* __restrict__ done) {
  const int wave = threadIdx.x >> 6;
  const int lane = threadIdx.x & 63;
  const int row  = blockIdx.x * 4 + wave;   // grid 2048 blocks -> 8192 rows

  const float* src = (row < 4096) ? (feat + (size_t)row * DDIM)
                                  : (pos + (size_t)(row - 4096) * DDIM);
  float4 v = ((const float4*)src)[lane];    // 4 contiguous fp32 per lane

  ushort4 o;
  o.x = f2bf(v.x); o.y = f2bf(v.y); o.z = f2bf(v.z); o.w = f2bf(v.w);
  ((ushort4*)(fb + (size_t)row * DDIM))[lane] = o;

  float ss = v.x*v.x + v.y*v.y + v.z*v.z + v.w*v.w;
  #pragma unroll
  for (int m = 1; m < 64; m <<= 1) ss += __shfl_xor(ss, m, 64);
  if (lane == 0) inv_w[row] = 1.0f / sqrtf(ss);

  const int tid = blockIdx.x * 256 + threadIdx.x;
  if (tid < NROWS) { S_all[tid] = 0.0f; S_pos[tid] = 0.0f; }
  if (tid == 0) *done = 0u;
}

// Kernel 2: fused f@f^T (bf16 MFMA) + exp(z-10) masked sums, UPPER-TRI tiles,
// diagonal-order enumeration. BK=64: 4 staging iterations (half the
// barrier-drain events of r5's BK=32; round-5 ledger put ~50% of per-tile
// cycles in K-loop stalls). The LAST block to finish also performs the final
// log-reduction (removes the milnce_final launch; ~constant 60us of non-gemm
// time across r2-r5 is dominated by per-dispatch overhead).
__global__ void __launch_bounds__(256)
milnce_gemm(const unsigned short* __restrict__ fb, const float* __restrict__ inv_w,
            const int* __restrict__ labels, float* __restrict__ S_all,
            float* __restrict__ S_pos, unsigned int* __restrict__ done,
            float* __restrict__ out) {
  __shared__ __align__(16) char smem[SMEM_BYTES];
  unsigned short* ldsA = (unsigned short*)smem;            // 16 KB staging
  unsigned short* ldsB = (unsigned short*)(smem + 16384);  // 16 KB staging
  float2* colAP = (float2*)smem;                           // epilogue (aliased)
  float2* rowAP = (float2*)(smem + ROWAP_OFF);
  unsigned int* lastFlag = (unsigned int*)(smem + 24064);
  float* red = (float*)(smem + 24128);

  // Decode linear tile id -> (bi, bj) along diagonals: d = bj - bi = 0..63,
  // diagonal d has 64-d tiles (distinct strips within a diagonal -> no
  // S-cacheline contention between concurrently-resident blocks).
  int t = blockIdx.x, d = 0, rem = NTILE;
  while (t >= rem) { t -= rem; ++d; --rem; }
  const int bi = t, bj = t + d;

  const int tid  = threadIdx.x;
  const int wave = tid >> 6;
  const int lane = tid & 63;
  const int quad = lane >> 4;
  const int l15  = lane & 15;
  const int wm   = wave >> 1;   // 2x2 wave grid over 128x128
  const int wn   = wave & 1;
  const int rowBase = bi * BM;
  const int colBase = bj * BN;

  f32x4 acc[4][4];
  #pragma unroll
  for (int i = 0; i < 4; ++i)
    #pragma unroll
    for (int j = 0; j < 4; ++j) acc[i][j] = (f32x4){0.f, 0.f, 0.f, 0.f};

  // Staging (BK=64): rows are 8 slices of 16B. Slot s = r*256 + tid
  // (r=round 0..3): row = r*32 + (tid>>3), LDS slice sl = tid&7 holding
  // global slice g = sl ^ (row&7)  [(r*32)&7 == 0, so row&7 == (tid>>3)&7].
  // Reader recovers exact global k for both A and B, so k-alignment is exact.
  const int srow = tid >> 3;
  const int gsl  = (tid & 7) ^ (srow & 7);
  const unsigned short* baseA = fb + (size_t)(rowBase + srow) * DDIM + gsl * 8;
  const unsigned short* baseB = fb + (size_t)(colBase + srow) * DDIM + gsl * 8;
  unsigned short* lbA = ldsA + wave * 512;   // wave-uniform; slot elems = slot*8
  unsigned short* lbB = ldsB + wave * 512;

  #pragma unroll
  for (int kt = 0; kt < DDIM / BK; ++kt) {
    __syncthreads();                       // protect LDS reuse
    #pragma unroll
    for (int r = 0; r < 4; ++r) {
      load_lds16(baseA + r * (32 * DDIM) + kt * BK, lbA + r * 2048);
      load_lds16(baseB + r * (32 * DDIM) + kt * BK, lbB + r * 2048);
    }
    __syncthreads();                       // drains vmcnt (compiler-inserted)

    #pragma unroll
    for (int h = 0; h < 2; ++h) {
      // LDS slice for global slice (h*4+quad) of row r: (h*4+quad) ^ (r&7),
      // r&7 == l15&7 for fragment rows. Bank starts = 8 positions x 8 lanes
      // (iso-structural to r2's measured-zero-conflict pattern).
      const int xsl = ((h * 4 + quad) ^ (l15 & 7)) * 8;
      short8 a[4], b[4];
      #pragma unroll
      for (int mi = 0; mi < 4; ++mi)
        a[mi] = *(const short8*)&ldsA[(wm * 64 + mi * 16 + l15) * BK + xsl];
      #pragma unroll
      for (int ni = 0; ni < 4; ++ni)
        b[ni] = *(const short8*)&ldsB[(wn * 64 + ni * 16 + l15) * BK + xsl];

      #pragma unroll
      for (int mi = 0; mi < 4; ++mi)
        #pragma unroll
        for (int ni = 0; ni < 4; ++ni)
          acc[mi][ni] = __builtin_amdgcn_mfma_f32_16x16x32_bf16(a[mi], b[ni], acc[mi][ni], 0, 0, 0);
    }
  }

  __syncthreads();   // staging LDS is dead; safe to alias with epilogue scratch

  // Epilogue. C/D layout (16x16x32): col = lane&15, row = quad*4 + reg.
  // e = exp2(z*L2E - 10*L2E); (e, e_pos) packed as float2 -> v_pk_add_f32.
  const float SHIFT = 10.0f * L2E;
  float cf[4]; int cl[4], colg[4];
  #pragma unroll
  for (int ni = 0; ni < 4; ++ni) {
    colg[ni] = colBase + wn * 64 + ni * 16 + l15;
    cf[ni]   = inv_w[colg[ni]] * (10.0f * L2E);
    cl[ni]   = labels[colg[ni] & 4095];   // concat duplicates labels
  }

  const bool offdiag = (bi != bj);

  float2 capk[4] = {{0.f,0.f},{0.f,0.f},{0.f,0.f},{0.f,0.f}};

  if (offdiag) {
    #pragma unroll
    for (int mi = 0; mi < 4; ++mi) {
      const int rbase = wm * 64 + mi * 16 + quad * 4;
      const float4 rf4 = *(const float4*)&inv_w[rowBase + rbase];
      const int4   rl4 = *(const int4*)&labels[(rowBase + rbase) & 4095];
      #pragma unroll
      for (int r = 0; r < 4; ++r) {
        const float rf = (r == 0) ? rf4.x : (r == 1) ? rf4.y : (r == 2) ? rf4.z : rf4.w;
        const int   rl = (r == 0) ? rl4.x : (r == 1) ? rl4.y : (r == 2) ? rl4.z : rl4.w;
        float sx = 0.f, sy = 0.f;
        #pragma unroll
        for (int ni = 0; ni < 4; ++ni) {
          float e  = exp2f(acc[mi][ni][r] * rf * cf[ni] - SHIFT);
          float ep = (rl == cl[ni]) ? e : 0.f;   // no diagonal here (bi != bj)
          capk[ni].x += e; capk[ni].y += ep;
          sx += e; sy += ep;
        }
        rowAP[(rbase + r) * ROW_STRIDE2 + wn * 16 + l15] = make_float2(sx, sy);
      }
    }
  } else {
    #pragma unroll
    for (int mi = 0; mi < 4; ++mi) {
      const int rbase = wm * 64 + mi * 16 + quad * 4;
      const float4 rf4 = *(const float4*)&inv_w[rowBase + rbase];
      const int4   rl4 = *(const int4*)&labels[(rowBase + rbase) & 4095];
      #pragma unroll
      for (int r = 0; r < 4; ++r) {
        const float rf = (r == 0) ? rf4.x : (r == 1) ? rf4.y : (r == 2) ? rf4.z : rf4.w;
        const int   rl = (r == 0) ? rl4.x : (r == 1) ? rl4.y : (r == 2) ? rl4.z : rl4.w;
        const int rowg = rowBase + rbase + r;
        #pragma unroll
        for (int ni = 0; ni < 4; ++ni) {
          float e = exp2f(acc[mi][ni][r] * rf * cf[ni] - SHIFT);
          if (rowg == colg[ni]) e = 0.f;         // mask diagonal entries
          float ep = (rl == cl[ni]) ? e : 0.f;
          capk[ni].x += e; capk[ni].y += ep;
        }
      }
    }
  }

  // Column partials -> LDS (4 quad slots per column), conflict-free stride.
  #pragma unroll
  for (int ni = 0; ni < 4; ++ni)
    colAP[(wn * 64 + ni * 16 + l15) * COL_STRIDE2 + quad] = capk[ni];

  __syncthreads();

  if (tid < 128) {
    // Column commit: sum 4 quad partials, one coalesced 64-lane atomic each.
    const float2* cp = &colAP[tid * COL_STRIDE2];
    float2 c0 = cp[0], c1 = cp[1], c2 = cp[2], c3 = cp[3];
    float sx = (c0.x + c1.x) + (c2.x + c3.x);
    float sy = (c0.y + c1.y) + (c2.y + c3.y);
    atomicAdd(&S_all[colBase + tid], sx);
    atomicAdd(&S_pos[colBase + tid], sy);
  } else if (offdiag) {
    // Row commit (== skipped transposed tile's columns): sum 16 lane partials.
    const int rr = tid - 128;
    const float2* rp = &rowAP[rr * ROW_STRIDE2];
    float sx = 0.f, sy = 0.f;
    #pragma unroll
    for (int i = 0; i < 16; ++i) { sx += rp[i].x; sy += rp[i].y; }
    atomicAdd(&S_all[rowBase + rr], sx);
    atomicAdd(&S_pos[rowBase + rr], sy);
  }

  // --- Fused finalize: last block to finish reduces S into the scalar loss.
  // Order-independent (G16): device-scope atomics + fence; reader uses
  // agent-scope atomic loads (bypass L1; S lines may live in other XCDs' L2).
  __syncthreads();                 // all commits of this block issued & drained
  if (tid == 0) {
    __threadfence();               // order our S-adds before the counter bump
    *lastFlag = (atomicAdd(done, 1u) == NTRI - 1) ? 1u : 0u;
  }
  __syncthreads();
  if (*lastFlag) {
    __threadfence();
    float s = 0.f;
    for (int i = tid; i < NROWS; i += 256) {
      float sa = __hip_atomic_load(&S_all[i], __ATOMIC_RELAXED, __HIP_MEMORY_SCOPE_AGENT);
      float sp = __hip_atomic_load(&S_pos[i], __ATOMIC_RELAXED, __HIP_MEMORY_SCOPE_AGENT);
      s += __logf(sa) - __logf(sp);   // +10 shifts cancel between the logs
    }
    #pragma unroll
    for (int m = 1; m < 64; m <<= 1) s += __shfl_xor(s, m, 64);
    if (lane == 0) red[wave] = s;
    __syncthreads();
    if (tid == 0) out[0] = (red[0] + red[1]) + (red[2] + red[3]);
  }
}

extern "C" void kernel_launch(void* const* d_in, const int* in_sizes, int n_in,
                              void* d_out, int out_size, void* d_ws, size_t ws_size,
                              hipStream_t stream) {
  const float* feat   = (const float*)d_in[0];
  const float* pos    = (const float*)d_in[1];
  const int*   labels = (const int*)d_in[2];

  char* ws = (char*)d_ws;
  unsigned short* fb    = (unsigned short*)ws;              // 4 MB bf16 concat
  float*          inv_w = (float*)(ws + WS_INVW);
  float*          S_all = (float*)(ws + WS_SALL);
  float*          S_pos = (float*)(ws + WS_SPOS);
  unsigned int*   done  = (unsigned int*)(ws + WS_DONE);
  float*          out   = (float*)d_out;

  hipLaunchKernelGGL(milnce_prep, dim3(NROWS / 4), dim3(256), 0, stream,
                     feat, pos, fb, inv_w, S_all, S_pos, done);
  hipLaunchKernelGGL(milnce_gemm, dim3(NTRI), dim3(256), 0, stream,
                     fb, inv_w, labels, S_all, S_pos, done, out);
}

// Round 7
// 119.619 us; speedup vs baseline: 1.1647x; 1.1647x over previous
//
#include <hip/hip_runtime.h>
#include <hip/hip_bf16.h>
#include <stdint.h>

// Problem constants (fixed shapes from reference: B=4096, D=256, N=2B)
#define NROWS 8192
#define DDIM  256
#define BM    128
#define BN    128
#define BK    32
#define NTILE (NROWS / BM)              // 64 tile-rows
#define NTRI  (NTILE * (NTILE + 1) / 2) // 2080 upper-tri tiles
#define L2E   1.44269504088896340736f

// LDS epilogue layout (aliases the staging buffers after the K-loop):
//   colAP: float2 [128 cols][5 slots]  @0     = 5120 B (stride 10 dw: conflict-free)
//   rowAP: float2 [128 rows][18 slots] @5120  = 18432 B (stride 36 dw = 16-bank
//          offset -> uniform 2-way = free)
//   lastFlag/red for fused finalize @23552.
#define COL_STRIDE2 5
#define ROW_STRIDE2 18
#define ROWAP_OFF   5120
#define FLAG_OFF    23552
#define SMEM_BYTES  23680

// Workspace layout:
#define WS_INVW (4u * 1024 * 1024)
#define WS_SALL (WS_INVW + 32 * 1024)
#define WS_SPOS (WS_SALL + 32 * 1024)
#define WS_DONE (WS_SPOS + 32 * 1024)

typedef __attribute__((ext_vector_type(8))) short short8;
typedef __attribute__((ext_vector_type(4))) float f32x4;

typedef const __attribute__((address_space(1))) uint32_t glb_u32;
typedef __attribute__((address_space(3))) uint32_t lds_u32;

__device__ __forceinline__ void load_lds16(const unsigned short* g, unsigned short* l) {
  // 16B per lane, LDS dest = wave-uniform base + lane*16 (HW scatter)
  __builtin_amdgcn_global_load_lds((glb_u32*)g, (lds_u32*)l, 16, 0, 0);
}

__device__ __forceinline__ unsigned short f2bf(float x) {
  __hip_bfloat16 h = __float2bfloat16(x);
  return *reinterpret_cast<unsigned short*>(&h);
}

// Kernel 1: build bf16 concat(f), inv norms (fp32), zero S arrays + done flag.
__global__ void __launch_bounds__(256)
milnce_prep(const float* __restrict__ feat, const float* __restrict__ pos,
            unsigned short* __restrict__ fb, float* __restrict__ inv_w,
            float* __restrict__ S_all, float* __restrict__ S_pos,
            unsigned int* __restrict__ done) {
  const int wave = threadIdx.x >> 6;
  const int lane = threadIdx.x & 63;
  const int row  = blockIdx.x * 4 + wave;   // grid 2048 blocks -> 8192 rows

  const float* src = (row < 4096) ? (feat + (size_t)row * DDIM)
                                  : (pos + (size_t)(row - 4096) * DDIM);
  float4 v = ((const float4*)src)[lane];    // 4 contiguous fp32 per lane

  ushort4 o;
  o.x = f2bf(v.x); o.y = f2bf(v.y); o.z = f2bf(v.z); o.w = f2bf(v.w);
  ((ushort4*)(fb + (size_t)row * DDIM))[lane] = o;

  float ss = v.x*v.x + v.y*v.y + v.z*v.z + v.w*v.w;
  #pragma unroll
  for (int m = 1; m < 64; m <<= 1) ss += __shfl_xor(ss, m, 64);
  if (lane == 0) inv_w[row] = 1.0f / sqrtf(ss);

  const int tid = blockIdx.x * 256 + threadIdx.x;
  if (tid < NROWS) { S_all[tid] = 0.0f; S_pos[tid] = 0.0f; }
  if (tid == 0) *done = 0u;
}

// Kernel 2: fused f@f^T (bf16 MFMA) + exp(z-10) masked sums, UPPER-TRI tiles,
// diagonal-order enumeration, r5's proven BK=32 K-loop (44.6us; r6's BK=64 +
// __threadfence() fusion regressed 2x -- replay counters showed full cache
// re-fetch every dispatch, fingerprinting the per-block device fence's cache
// invalidation). Fused finalize is FENCE-FREE: __syncthreads() drains
// vmcnt(0), so this block's device-scope S-atomics are globally performed
// before the done bump; reader uses agent-scope atomic loads (bypass L1/L2).
__global__ void __launch_bounds__(256)
milnce_gemm(const unsigned short* __restrict__ fb, const float* __restrict__ inv_w,
            const int* __restrict__ labels, float* __restrict__ S_all,
            float* __restrict__ S_pos, unsigned int* __restrict__ done,
            float* __restrict__ out) {
  __shared__ __align__(16) char smem[SMEM_BYTES];
  unsigned short* ldsA = (unsigned short*)smem;            // 8 KB staging
  unsigned short* ldsB = (unsigned short*)(smem + 8192);   // 8 KB staging
  float2* colAP = (float2*)smem;                           // epilogue (aliased)
  float2* rowAP = (float2*)(smem + ROWAP_OFF);
  unsigned int* lastFlag = (unsigned int*)(smem + FLAG_OFF);
  float* red = (float*)(smem + FLAG_OFF + 64);

  // Decode linear tile id -> (bi, bj) along diagonals: d = bj - bi = 0..63,
  // diagonal d has 64-d tiles (distinct strips within a diagonal -> no
  // S-cacheline contention between concurrently-resident blocks).
  int t = blockIdx.x, d = 0, rem = NTILE;
  while (t >= rem) { t -= rem; ++d; --rem; }
  const int bi = t, bj = t + d;

  const int tid  = threadIdx.x;
  const int wave = tid >> 6;
  const int lane = tid & 63;
  const int quad = lane >> 4;
  const int l15  = lane & 15;
  const int wm   = wave >> 1;   // 2x2 wave grid over 128x128
  const int wn   = wave & 1;
  const int rowBase = bi * BM;
  const int colBase = bj * BN;

  f32x4 acc[4][4];
  #pragma unroll
  for (int i = 0; i < 4; ++i)
    #pragma unroll
    for (int j = 0; j < 4; ++j) acc[i][j] = (f32x4){0.f, 0.f, 0.f, 0.f};

  // Staging: slot s (0..511) is 16B at LDS offset s*16; row = s>>2.
  // Swizzle: slot s holds global k-slice gsl = (s&3) ^ ((s>>3)&3).
  const int s0 = wave * 64 + lane;       // load 0
  const int s1 = s0 + 256;               // load 1
  const int r0 = s0 >> 2, g0 = (s0 & 3) ^ ((s0 >> 3) & 3);
  const int r1 = s1 >> 2, g1 = (s1 & 3) ^ ((s1 >> 3) & 3);
  const unsigned short* gA0 = fb + (size_t)(rowBase + r0) * DDIM + g0 * 8;
  const unsigned short* gA1 = fb + (size_t)(rowBase + r1) * DDIM + g1 * 8;
  const unsigned short* gB0 = fb + (size_t)(colBase + r0) * DDIM + g0 * 8;
  const unsigned short* gB1 = fb + (size_t)(colBase + r1) * DDIM + g1 * 8;
  unsigned short* lA0 = ldsA + (size_t)(wave * 64) * 8;          // wave-uniform bases
  unsigned short* lA1 = ldsA + (size_t)(wave * 64 + 256) * 8;
  unsigned short* lB0 = ldsB + (size_t)(wave * 64) * 8;
  unsigned short* lB1 = ldsB + (size_t)(wave * 64 + 256) * 8;

  // Reader swizzle: global slice `quad` of row r lives at LDS slice
  // xsl = quad ^ ((r>>1)&3) = quad ^ ((l15>>1)&3).
  const int xsl = quad ^ ((l15 >> 1) & 3);

  #pragma unroll
  for (int kt = 0; kt < DDIM / BK; ++kt) {
    const int ko = kt * BK;
    __syncthreads();                       // protect LDS reuse
    load_lds16(gA0 + ko, lA0);
    load_lds16(gA1 + ko, lA1);
    load_lds16(gB0 + ko, lB0);
    load_lds16(gB1 + ko, lB1);
    __syncthreads();                       // drains vmcnt (compiler-inserted)

    short8 a[4], b[4];
    #pragma unroll
    for (int mi = 0; mi < 4; ++mi)
      a[mi] = *(const short8*)&ldsA[(wm * 64 + mi * 16 + l15) * BK + xsl * 8];
    #pragma unroll
    for (int ni = 0; ni < 4; ++ni)
      b[ni] = *(const short8*)&ldsB[(wn * 64 + ni * 16 + l15) * BK + xsl * 8];

    #pragma unroll
    for (int mi = 0; mi < 4; ++mi)
      #pragma unroll
      for (int ni = 0; ni < 4; ++ni)
        acc[mi][ni] = __builtin_amdgcn_mfma_f32_16x16x32_bf16(a[mi], b[ni], acc[mi][ni], 0, 0, 0);
  }

  __syncthreads();   // staging LDS is dead; safe to alias with epilogue scratch

  // Epilogue. C/D layout (16x16x32): col = lane&15, row = quad*4 + reg.
  // e = exp2(z*L2E - 10*L2E); (e, e_pos) packed as float2 -> v_pk_add_f32.
  const float SHIFT = 10.0f * L2E;
  float cf[4]; int cl[4], colg[4];
  #pragma unroll
  for (int ni = 0; ni < 4; ++ni) {
    colg[ni] = colBase + wn * 64 + ni * 16 + l15;
    cf[ni]   = inv_w[colg[ni]] * (10.0f * L2E);
    cl[ni]   = labels[colg[ni] & 4095];   // concat duplicates labels
  }

  const bool offdiag = (bi != bj);

  float2 capk[4] = {{0.f,0.f},{0.f,0.f},{0.f,0.f},{0.f,0.f}};

  if (offdiag) {
    #pragma unroll
    for (int mi = 0; mi < 4; ++mi) {
      const int rbase = wm * 64 + mi * 16 + quad * 4;
      const float4 rf4 = *(const float4*)&inv_w[rowBase + rbase];
      const int4   rl4 = *(const int4*)&labels[(rowBase + rbase) & 4095];
      #pragma unroll
      for (int r = 0; r < 4; ++r) {
        const float rf = (r == 0) ? rf4.x : (r == 1) ? rf4.y : (r == 2) ? rf4.z : rf4.w;
        const int   rl = (r == 0) ? rl4.x : (r == 1) ? rl4.y : (r == 2) ? rl4.z : rl4.w;
        float sx = 0.f, sy = 0.f;
        #pragma unroll
        for (int ni = 0; ni < 4; ++ni) {
          float e  = exp2f(acc[mi][ni][r] * rf * cf[ni] - SHIFT);
          float ep = (rl == cl[ni]) ? e : 0.f;   // no diagonal here (bi != bj)
          capk[ni].x += e; capk[ni].y += ep;
          sx += e; sy += ep;
        }
        rowAP[(rbase + r) * ROW_STRIDE2 + wn * 16 + l15] = make_float2(sx, sy);
      }
    }
  } else {
    #pragma unroll
    for (int mi = 0; mi < 4; ++mi) {
      const int rbase = wm * 64 + mi * 16 + quad * 4;
      const float4 rf4 = *(const float4*)&inv_w[rowBase + rbase];
      const int4   rl4 = *(const int4*)&labels[(rowBase + rbase) & 4095];
      #pragma unroll
      for (int r = 0; r < 4; ++r) {
        const float rf = (r == 0) ? rf4.x : (r == 1) ? rf4.y : (r == 2) ? rf4.z : rf4.w;
        const int   rl = (r == 0) ? rl4.x : (r == 1) ? rl4.y : (r == 2) ? rl4.z : rl4.w;
        const int rowg = rowBase + rbase + r;
        #pragma unroll
        for (int ni = 0; ni < 4; ++ni) {
          float e = exp2f(acc[mi][ni][r] * rf * cf[ni] - SHIFT);
          if (rowg == colg[ni]) e = 0.f;         // mask diagonal entries
          float ep = (rl == cl[ni]) ? e : 0.f;
          capk[ni].x += e; capk[ni].y += ep;
        }
      }
    }
  }

  // Column partials -> LDS (4 quad slots per column), conflict-free stride.
  #pragma unroll
  for (int ni = 0; ni < 4; ++ni)
    colAP[(wn * 64 + ni * 16 + l15) * COL_STRIDE2 + quad] = capk[ni];

  __syncthreads();

  if (tid < 128) {
    // Column commit: sum 4 quad partials, one coalesced 64-lane atomic each.
    const float2* cp = &colAP[tid * COL_STRIDE2];
    float2 c0 = cp[0], c1 = cp[1], c2 = cp[2], c3 = cp[3];
    float sx = (c0.x + c1.x) + (c2.x + c3.x);
    float sy = (c0.y + c1.y) + (c2.y + c3.y);
    atomicAdd(&S_all[colBase + tid], sx);
    atomicAdd(&S_pos[colBase + tid], sy);
  } else if (offdiag) {
    // Row commit (== skipped transposed tile's columns): sum 16 lane partials.
    const int rr = tid - 128;
    const float2* rp = &rowAP[rr * ROW_STRIDE2];
    float sx = 0.f, sy = 0.f;
    #pragma unroll
    for (int i = 0; i < 16; ++i) { sx += rp[i].x; sy += rp[i].y; }
    atomicAdd(&S_all[rowBase + rr], sx);
    atomicAdd(&S_pos[rowBase + rr], sy);
  }

  // --- Fused finalize (fence-free). __syncthreads() emits s_waitcnt vmcnt(0)
  // before s_barrier, so this block's S atomicAdds (device-scope RMWs executed
  // at the coherence point) are globally performed before the done bump below.
  // NO __threadfence(): round-6 showed the per-block device fence invalidates
  // caches (replays re-fetched 22 MB -> 2x dilation).
  __syncthreads();
  if (tid == 0) {
    unsigned int old = __hip_atomic_fetch_add(done, 1u, __ATOMIC_RELAXED,
                                              __HIP_MEMORY_SCOPE_AGENT);
    *lastFlag = (old == NTRI - 1) ? 1u : 0u;
  }
  __syncthreads();
  if (*lastFlag) {
    float s = 0.f;
    for (int i = tid; i < NROWS; i += 256) {
      float sa = __hip_atomic_load(&S_all[i], __ATOMIC_RELAXED, __HIP_MEMORY_SCOPE_AGENT);
      float sp = __hip_atomic_load(&S_pos[i], __ATOMIC_RELAXED, __HIP_MEMORY_SCOPE_AGENT);
      s += __logf(sa) - __logf(sp);   // +10 shifts cancel between the logs
    }
    #pragma unroll
    for (int m = 1; m < 64; m <<= 1) s += __shfl_xor(s, m, 64);
    if (lane == 0) red[wave] = s;
    __syncthreads();
    if (tid == 0) out[0] = (red[0] + red[1]) + (red[2] + red[3]);
  }
}

extern "C" void kernel_launch(void* const* d_in, const int* in_sizes, int n_in,
                              void* d_out, int out_size, void* d_ws, size_t ws_size,
                              hipStream_t stream) {
  const float* feat   = (const float*)d_in[0];
  const float* pos    = (const float*)d_in[1];
  const int*   labels = (const int*)d_in[2];

  char* ws = (char*)d_ws;
  unsigned short* fb    = (unsigned short*)ws;              // 4 MB bf16 concat
  float*          inv_w = (float*)(ws + WS_INVW);
  float*          S_all = (float*)(ws + WS_SALL);
  float*          S_pos = (float*)(ws + WS_SPOS);
  unsigned int*   done  = (unsigned int*)(ws + WS_DONE);
  float*          out   = (float*)d_out;

  hipLaunchKernelGGL(milnce_prep, dim3(NROWS / 4), dim3(256), 0, stream,
                     feat, pos, fb, inv_w, S_all, S_pos, done);
  hipLaunchKernelGGL(milnce_gemm, dim3(NTRI), dim3(256), 0, stream,
                     fb, inv_w, labels, S_all, S_pos, done, out);
}